// Round 9
// baseline (2688.054 us; speedup 1.0000x reference)
//
#include <hip/hip_runtime.h>
#include <hip/hip_bf16.h>

#define NS 32   // n_state
#define NI 16   // n_input
#define NA 48   // n_all
#define TT 64   // horizon
#define HT 32   // half horizon

// LQR: backward Riccati + forward rollout, half-horizon K storage.
//   sweep A: t=63..0, store K_t (f32) for t<32
//   fwd 1  : t=0..31  (emit tau, record x)
//   sweep B: t=63..32, store K_t for t>=32
//   fwd 2  : t=32..63
//   sweep C: t=63..0, emit mu_t = P_t x_t (mu_0 = -P_0 x_0)
// Single block, 256 threads, ~119 KiB LDS, NO d_ws. All Riccati state f64.
// OUTPUT IS FLOAT32 (reference returns f32; earlier bf16 writes were the
// sole cause of the 13.375 failure signature).
__launch_bounds__(256, 1)
__global__ void lqr_kernel(const float* __restrict__ Ag,
                           const float* __restrict__ Bg,
                           const float* __restrict__ Cg,
                           const float* __restrict__ x0g,
                           float* __restrict__ out)
{
    __shared__ float  sKh[HT][NI][NS];  // 65536 B  half-horizon gains (f32)
    __shared__ float  sXT[TT][NS];      //  8192 B  x trajectory (f32)
    __shared__ double sA[NS][NS];       //  8192 B
    __shared__ double sB[NS][NI];       //  4096 B
    __shared__ double sP[NS][NS];       //  8192 B
    __shared__ double sPA[NS][NS];      //  8192 B
    __shared__ double sPB[NS][NI];      //  4096 B
    __shared__ double sHs[NI][NS];      //  4096 B
    __shared__ double sKt[NI][NS];      //  4096 B
    __shared__ double sGb[2 * NI * NI]; //  4096 B  GJ double-buffer
    __shared__ double sx[NS];           //   256 B
    __shared__ double su[NI];           //   128 B   total ~119 KB

    const int tid = threadIdx.x;
    const int gi = tid >> 4, gj = tid & 15;        // 16x16 roles
    const int pi = tid >> 3, pj0 = (tid & 7) * 4;  // 32x32 roles
    const int pb0 = (tid & 7) * 2;                 // 32x16 roles

    for (int idx = tid; idx < NS * NS; idx += 256) sA[idx / NS][idx % NS] = (double)Ag[idx];
    for (int idx = tid; idx < NS * NI; idx += 256) sB[idx / NI][idx % NI] = (double)Bg[idx];
    __syncthreads();

    // One Riccati step: on entry sP = P_{t+1}, on exit sP = P_t.
    auto step = [&](int t, bool storeK, int kbase, bool emitMu) {
        const float* Ct = Cg + t * NA * NA;   // [48][48] row-major

        // PA = P*A (32x32), PB = P*B (32x16)
        {
            double a0 = 0, a1 = 0, a2 = 0, a3 = 0;
            for (int k = 0; k < NS; ++k) {
                const double p = sP[pi][k];
                a0 += p * sA[k][pj0 + 0]; a1 += p * sA[k][pj0 + 1];
                a2 += p * sA[k][pj0 + 2]; a3 += p * sA[k][pj0 + 3];
            }
            sPA[pi][pj0 + 0] = a0; sPA[pi][pj0 + 1] = a1;
            sPA[pi][pj0 + 2] = a2; sPA[pi][pj0 + 3] = a3;
            double b0 = 0, b1 = 0;
            for (int k = 0; k < NS; ++k) {
                const double p = sP[pi][k];
                b0 += p * sB[k][pb0 + 0]; b1 += p * sB[k][pb0 + 1];
            }
            sPB[pi][pb0 + 0] = b0; sPB[pi][pb0 + 1] = b1;
        }
        __syncthreads();

        // G = R + B^T P B  (into sGb[0]);  Hs = S^T + B^T P A
        {
            double acc = (double)Ct[(NS + gi) * NA + (NS + gj)];
            for (int k = 0; k < NS; ++k) acc += sB[k][gi] * sPB[k][gj];
            sGb[gi * NI + gj] = acc;
            const int j0 = gj * 2;
            double a0 = (double)Ct[(j0 + 0) * NA + (NS + gi)];
            double a1 = (double)Ct[(j0 + 1) * NA + (NS + gi)];
            for (int k = 0; k < NS; ++k) {
                const double b = sB[k][gi];
                a0 += b * sPA[k][j0 + 0]; a1 += b * sPA[k][j0 + 1];
            }
            sHs[gi][j0 + 0] = a0; sHs[gi][j0 + 1] = a1;
        }
        __syncthreads();

        // Gauss-Jordan sweep inverse of SPD G (f64, double-buffered; result buf 0)
        for (int k = 0; k < NI; ++k) {
            const double* src = sGb + (k & 1) * NI * NI;
            double* dst = sGb + ((k + 1) & 1) * NI * NI;
            const double ip = 1.0 / src[k * NI + k];
            double v;
            if (gi == k && gj == k)      v = ip;
            else if (gi == k)            v = src[k * NI + gj] * ip;
            else if (gj == k)            v = -src[gi * NI + k] * ip;
            else v = src[gi * NI + gj] - src[gi * NI + k] * src[k * NI + gj] * ip;
            dst[gi * NI + gj] = v;
            __syncthreads();
        }

        // K_t = G^{-1} Hs (f64 working copy; optional f32 store)
        {
            const int j0 = gj * 2;
            double a0 = 0, a1 = 0;
            for (int k = 0; k < NI; ++k) {
                const double g = sGb[gi * NI + k];
                a0 += g * sHs[k][j0 + 0]; a1 += g * sHs[k][j0 + 1];
            }
            sKt[gi][j0 + 0] = a0; sKt[gi][j0 + 1] = a1;
            if (storeK) {
                sKh[t - kbase][gi][j0 + 0] = (float)a0;
                sKh[t - kbase][gi][j0 + 1] = (float)a1;
            }
        }
        __syncthreads();

        // P_t = Q + A^T PA - Hs^T K
        {
            double a0 = (double)Ct[pi * NA + pj0 + 0];
            double a1 = (double)Ct[pi * NA + pj0 + 1];
            double a2 = (double)Ct[pi * NA + pj0 + 2];
            double a3 = (double)Ct[pi * NA + pj0 + 3];
            for (int k = 0; k < NS; ++k) {
                const double a = sA[k][pi];
                a0 += a * sPA[k][pj0 + 0]; a1 += a * sPA[k][pj0 + 1];
                a2 += a * sPA[k][pj0 + 2]; a3 += a * sPA[k][pj0 + 3];
            }
            for (int k = 0; k < NI; ++k) {
                const double h = sHs[k][pi];
                a0 -= h * sKt[k][pj0 + 0]; a1 -= h * sKt[k][pj0 + 1];
                a2 -= h * sKt[k][pj0 + 2]; a3 -= h * sKt[k][pj0 + 3];
            }
            sP[pi][pj0 + 0] = a0; sP[pi][pj0 + 1] = a1;
            sP[pi][pj0 + 2] = a2; sP[pi][pj0 + 3] = a3;
        }
        __syncthreads();

        // symmetrize P
        {
            const double m0 = 0.5 * (sP[pi][pj0 + 0] + sP[pj0 + 0][pi]);
            const double m1 = 0.5 * (sP[pi][pj0 + 1] + sP[pj0 + 1][pi]);
            const double m2 = 0.5 * (sP[pi][pj0 + 2] + sP[pj0 + 2][pi]);
            const double m3 = 0.5 * (sP[pi][pj0 + 3] + sP[pj0 + 3][pi]);
            __syncthreads();
            sP[pi][pj0 + 0] = m0; sP[pi][pj0 + 1] = m1;
            sP[pi][pj0 + 2] = m2; sP[pi][pj0 + 3] = m3;
        }
        __syncthreads();

        // mu_t = P_t x_t (sweep C); mu_0 = -P_0 x_0
        if (emitMu && tid < NS) {
            double acc = 0.0;
            for (int k = 0; k < NS; ++k) acc += sP[tid][k] * (double)sXT[t][k];
            if (t == 0) acc = -acc;
            out[NA * TT + t * NS + tid] = (float)acc;
        }
    };

    // Backward sweep from t=TT-1 down to tlo; store K for t in [klo, khi).
    auto sweep = [&](int tlo, int klo, int khi, bool emitMu) {
        for (int idx = tid; idx < NS * NS; idx += 256) sP[idx / NS][idx % NS] = 0.0;
        __syncthreads();
        for (int t = TT - 1; t >= tlo; --t)
            step(t, (t >= klo && t < khi), klo, emitMu);
    };

    // Forward rollout over [t0, t1), gains in sKh[t - kbase]. sx persists.
    auto forward = [&](int t0, int t1, int kbase) {
        for (int t = t0; t < t1; ++t) {
            if (tid < NS) {
                sXT[t][tid] = (float)sx[tid];
                out[t * NA + tid] = (float)sx[tid];
            }
            if (tid >= 64 && tid < 64 + NI) {
                const int i = tid - 64;
                double acc = 0.0;
                for (int k = 0; k < NS; ++k)
                    acc += (double)sKh[t - kbase][i][k] * sx[k];
                su[i] = -acc;
                out[t * NA + NS + i] = (float)(-acc);
            }
            __syncthreads();
            // x_{t+1} = A x_t + B u_t  (register-staged, single buffer)
            double acc = 0.0;
            if (tid < NS) {
                for (int k = 0; k < NS; ++k) acc += sA[tid][k] * sx[k];
                for (int k = 0; k < NI; ++k) acc += sB[tid][k] * su[k];
            }
            __syncthreads();
            if (tid < NS) sx[tid] = acc;
            __syncthreads();
        }
    };

    // ---- schedule ----
    sweep(0, 0, HT, false);          // A: full sweep, store K_0..31
    if (tid < NS) sx[tid] = (double)x0g[tid];
    __syncthreads();
    forward(0, HT, 0);               // fwd 1: tau_0..31, x -> x_32
    sweep(HT, HT, TT, false);        // B: t=63..32, store K_32..63
    forward(HT, TT, HT);             // fwd 2: tau_32..63
    sweep(0, 0, 0, true);            // C: full sweep, emit mu
}

extern "C" void kernel_launch(void* const* d_in, const int* in_sizes, int n_in,
                              void* d_out, int out_size, void* d_ws, size_t ws_size,
                              hipStream_t stream) {
    // Bind by element count (A=1024, B=512, C=147456, x0=32), fallback dict order.
    const float *A = nullptr, *B = nullptr, *C = nullptr, *x0 = nullptr;
    for (int i = 0; i < n_in; ++i) {
        switch (in_sizes[i]) {
            case 1024:   A  = (const float*)d_in[i]; break;
            case 512:    B  = (const float*)d_in[i]; break;
            case 147456: C  = (const float*)d_in[i]; break;
            case 32:     x0 = (const float*)d_in[i]; break;
            default: break;
        }
    }
    if (!A || !B || !C || !x0) {
        A  = (const float*)d_in[0];
        B  = (const float*)d_in[1];
        C  = (const float*)d_in[2];
        x0 = (const float*)d_in[5];
    }

    lqr_kernel<<<1, 256, 0, stream>>>(A, B, C, x0, (float*)d_out);
}

// Round 11
// 2449.634 us; speedup vs baseline: 1.0973x; 1.0973x over previous
//
#include <hip/hip_runtime.h>

#define NS 32   // n_state
#define NI 16   // n_input
#define NA 48   // n_all
#define TT 64   // horizon
#define HT 32   // half horizon

// LQR: backward Riccati + forward rollout, half-horizon K storage.
// 4 barriers per Riccati step:
//   phase1: PA=P*A, PB=P*B                       (all 256)      | barrier A
//   phase2: wave0: G=R+B^T PB -> G^{-1} via register/__shfl GJ  |
//           waves1-3: Hs=S^T+B^T PA, Pp=Q+A^T PA (overlapped)   | barrier B
//   phase3: K = G^{-1} Hs                                        | barrier C
//   phase4: P = sym(Pp - Hs^T K)  [symmetrization fused, REQUIRED:
//           unsymmetrized f64 recursion diverges deterministically
//           (126976 signature, rounds 0/10)]                     | barrier D
// All Riccati state f64; K stored f32; OUTPUT f32 (round-9-proven).
__launch_bounds__(256, 1)
__global__ void lqr_kernel(const float* __restrict__ Ag,
                           const float* __restrict__ Bg,
                           const float* __restrict__ Cg,
                           const float* __restrict__ x0g,
                           float* __restrict__ out)
{
    __shared__ float  sKh[HT][NI][NS];  // 65536 B  half-horizon gains (f32)
    __shared__ float  sXT[TT][NS];      //  8192 B  x trajectory (f32)
    __shared__ double sA[NS][NS];       //  8192 B
    __shared__ double sB[NS][NI];       //  4096 B
    __shared__ double sP[NS][NS];       //  8192 B  Riccati state (f64)
    __shared__ double sPA[NS][NS];      //  8192 B  P*A
    __shared__ double sPB[NS][NI];      //  4096 B  P*B
    __shared__ double sHs[NI][NS];      //  4096 B  S^T + B^T P A
    __shared__ double sKt[NI][NS];      //  4096 B  K_t (f64)
    __shared__ double sGi[NI][NI];      //  2048 B  G^{-1} (written once by wave 0)
    __shared__ double sPp[NS][NS];      //  8192 B  Q + A^T P A
    __shared__ double sx[2][NS];        //   512 B
    __shared__ double su[NI];           //   128 B   total ~122.6 KB

    const int tid  = threadIdx.x;
    const int wid  = tid >> 6, lane = tid & 63;
    const int pi   = tid >> 3, pj0 = (tid & 7) * 4, pb0 = (tid & 7) * 2;
    const int ki   = tid >> 4, kj0 = (tid & 15) * 2;

    for (int idx = tid; idx < NS * NS; idx += 256) sA[idx >> 5][idx & 31] = (double)Ag[idx];
    for (int idx = tid; idx < NS * NI; idx += 256) sB[idx >> 4][idx & 15] = (double)Bg[idx];
    __syncthreads();

    // One Riccati step: entry sP = P_{t+1}, exit sP = P_t.  4 barriers.
    auto step = [&](int t, bool storeK, int kbase, bool emitMu) {
        const float* Ct = Cg + t * NA * NA;   // [48][48] row-major

        // ---- phase 1: PA (4 cols) + PB (2 cols) per thread ----
        {
            double a0 = 0, a1 = 0, a2 = 0, a3 = 0, b0 = 0, b1 = 0;
            for (int k = 0; k < NS; ++k) {
                const double p = sP[pi][k];
                a0 += p * sA[k][pj0 + 0]; a1 += p * sA[k][pj0 + 1];
                a2 += p * sA[k][pj0 + 2]; a3 += p * sA[k][pj0 + 3];
                b0 += p * sB[k][pb0 + 0]; b1 += p * sB[k][pb0 + 1];
            }
            sPA[pi][pj0 + 0] = a0; sPA[pi][pj0 + 1] = a1;
            sPA[pi][pj0 + 2] = a2; sPA[pi][pj0 + 3] = a3;
            sPB[pi][pb0 + 0] = b0; sPB[pi][pb0 + 1] = b1;
        }
        __syncthreads();                                   // barrier A

        // ---- phase 2 (overlapped) ----
        if (wid == 0) {
            // wave 0: G = R + B^T P B held as 4 f64/lane, then GJ inverse
            // entirely in registers via __shfl (race-free by construction).
            const int ri = lane & 15, cg = lane >> 4, jb = cg * 4;
            double g0 = (double)Ct[(NS + ri) * NA + NS + jb + 0];
            double g1 = (double)Ct[(NS + ri) * NA + NS + jb + 1];
            double g2 = (double)Ct[(NS + ri) * NA + NS + jb + 2];
            double g3 = (double)Ct[(NS + ri) * NA + NS + jb + 3];
            for (int k = 0; k < NS; ++k) {
                const double b = sB[k][ri];
                g0 += b * sPB[k][jb + 0]; g1 += b * sPB[k][jb + 1];
                g2 += b * sPB[k][jb + 2]; g3 += b * sPB[k][jb + 3];
            }
#pragma unroll
            for (int k = 0; k < NI; ++k) {
                const double myslot = ((k & 3) == 0) ? g0 : ((k & 3) == 1) ? g1
                                     : ((k & 3) == 2) ? g2 : g3;
                const int    plv  = k + ((k >> 2) << 4);      // lane of (k,k)
                const double piv  = __shfl(myslot, plv, 64);
                const double cv   = __shfl(myslot, ri + ((k >> 2) << 4), 64); // (ri,k)
                const double pr0  = __shfl(g0, k + (cg << 4), 64);            // (k,jb+j)
                const double pr1  = __shfl(g1, k + (cg << 4), 64);
                const double pr2  = __shfl(g2, k + (cg << 4), 64);
                const double pr3  = __shfl(g3, k + (cg << 4), 64);
                const double ip   = 1.0 / piv;
                const bool   rk   = (ri == k);
                g0 = rk ? ((jb + 0 == k) ? ip : pr0 * ip)
                        : ((jb + 0 == k) ? -cv * ip : g0 - cv * pr0 * ip);
                g1 = rk ? ((jb + 1 == k) ? ip : pr1 * ip)
                        : ((jb + 1 == k) ? -cv * ip : g1 - cv * pr1 * ip);
                g2 = rk ? ((jb + 2 == k) ? ip : pr2 * ip)
                        : ((jb + 2 == k) ? -cv * ip : g2 - cv * pr2 * ip);
                g3 = rk ? ((jb + 3 == k) ? ip : pr3 * ip)
                        : ((jb + 3 == k) ? -cv * ip : g3 - cv * pr3 * ip);
            }
            sGi[ri][jb + 0] = g0; sGi[ri][jb + 1] = g1;
            sGi[ri][jb + 2] = g2; sGi[ri][jb + 3] = g3;
        } else {
            // waves 1-3 (192 threads): Hs = S^T + B^T P A, Pp = Q + A^T P A
            const int e0 = tid - 64;
            for (int e = e0; e < NI * NS; e += 192) {
                const int i = e >> 5, j = e & 31;
                double acc = (double)Ct[j * NA + NS + i];
                for (int k = 0; k < NS; ++k) acc += sB[k][i] * sPA[k][j];
                sHs[i][j] = acc;
            }
            for (int e = e0; e < NS * NS; e += 192) {
                const int i = e >> 5, j = e & 31;
                double acc = (double)Ct[i * NA + j];
                for (int k = 0; k < NS; ++k) acc += sA[k][i] * sPA[k][j];
                sPp[i][j] = acc;
            }
        }
        __syncthreads();                                   // barrier B

        // ---- phase 3: K = G^{-1} Hs (2 cols per thread) ----
        {
            double a0 = 0, a1 = 0;
            for (int k = 0; k < NI; ++k) {
                const double g = sGi[ki][k];
                a0 += g * sHs[k][kj0 + 0];
                a1 += g * sHs[k][kj0 + 1];
            }
            sKt[ki][kj0 + 0] = a0; sKt[ki][kj0 + 1] = a1;
            if (storeK) {
                sKh[t - kbase][ki][kj0 + 0] = (float)a0;
                sKh[t - kbase][ki][kj0 + 1] = (float)a1;
            }
        }
        __syncthreads();                                   // barrier C

        // ---- phase 4: P_t = sym(Pp - Hs^T K), symmetrization fused ----
        {
            double r0, r1, r2, r3;
            {
                double a0 = sPp[pi][pj0 + 0], a1 = sPp[pi][pj0 + 1];
                double a2 = sPp[pi][pj0 + 2], a3 = sPp[pi][pj0 + 3];
                for (int k = 0; k < NI; ++k) {
                    const double h = sHs[k][pi];
                    a0 -= h * sKt[k][pj0 + 0]; a1 -= h * sKt[k][pj0 + 1];
                    a2 -= h * sKt[k][pj0 + 2]; a3 -= h * sKt[k][pj0 + 3];
                }
                // transposed-element expressions (same op order -> the owner
                // of (j,i) computes bit-identical values; sum is commutative
                // -> P exactly symmetric)
                double b0 = sPp[pj0 + 0][pi], b1 = sPp[pj0 + 1][pi];
                double b2 = sPp[pj0 + 2][pi], b3 = sPp[pj0 + 3][pi];
                for (int k = 0; k < NI; ++k) {
                    const double hk = sKt[k][pi];
                    b0 -= sHs[k][pj0 + 0] * hk; b1 -= sHs[k][pj0 + 1] * hk;
                    b2 -= sHs[k][pj0 + 2] * hk; b3 -= sHs[k][pj0 + 3] * hk;
                }
                r0 = 0.5 * (a0 + b0); r1 = 0.5 * (a1 + b1);
                r2 = 0.5 * (a2 + b2); r3 = 0.5 * (a3 + b3);
            }
            sP[pi][pj0 + 0] = r0; sP[pi][pj0 + 1] = r1;
            sP[pi][pj0 + 2] = r2; sP[pi][pj0 + 3] = r3;
        }
        __syncthreads();                                   // barrier D

        // mu_t = P_t x_t (pass C); mu_0 = -P_0 x_0. Read-only: no barrier.
        if (emitMu && tid < NS) {
            double acc = 0.0;
            for (int k = 0; k < NS; ++k) acc += sP[tid][k] * (double)sXT[t][k];
            if (t == 0) acc = -acc;
            out[NA * TT + t * NS + tid] = (float)acc;
        }
    };

    auto sweep = [&](int tlo, int klo, int khi, bool emitMu) {
        for (int idx = tid; idx < NS * NS; idx += 256) sP[idx >> 5][idx & 31] = 0.0;
        __syncthreads();
        for (int t = TT - 1; t >= tlo; --t)
            step(t, (t >= klo && t < khi), klo, emitMu);
    };

    int cur = 0;
    auto forward = [&](int t0, int t1, int kbase) {
        for (int t = t0; t < t1; ++t) {
            if (tid < NS) {
                const float xv = (float)sx[cur][tid];
                sXT[t][tid] = xv;
                out[t * NA + tid] = xv;
            } else if (tid >= 64 && tid < 64 + NI) {
                const int i = tid - 64;
                double acc = 0.0;
                for (int k = 0; k < NS; ++k)
                    acc += (double)sKh[t - kbase][i][k] * sx[cur][k];
                su[i] = -acc;
                out[t * NA + NS + i] = (float)(-acc);
            }
            __syncthreads();
            if (t < TT - 1) {
                if (tid < NS) {
                    double acc = 0.0;
                    for (int k = 0; k < NS; ++k) acc += sA[tid][k] * sx[cur][k];
                    for (int k = 0; k < NI; ++k) acc += sB[tid][k] * su[k];
                    sx[cur ^ 1][tid] = acc;
                }
                __syncthreads();
                cur ^= 1;
            }
        }
    };

    // ---- schedule (identical to passing round 9) ----
    sweep(0, 0, HT, false);          // A: full sweep, store K_0..31
    if (tid < NS) sx[0][tid] = (double)x0g[tid];
    __syncthreads();
    forward(0, HT, 0);               // fwd 1: tau_0..31
    sweep(HT, HT, TT, false);        // B: t=63..32, store K_32..63
    forward(HT, TT, HT);             // fwd 2: tau_32..63
    sweep(0, 0, 0, true);            // C: full sweep, emit mu
}

extern "C" void kernel_launch(void* const* d_in, const int* in_sizes, int n_in,
                              void* d_out, int out_size, void* d_ws, size_t ws_size,
                              hipStream_t stream) {
    // Bind by element count (A=1024, B=512, C=147456, x0=32), fallback dict order.
    const float *A = nullptr, *B = nullptr, *C = nullptr, *x0 = nullptr;
    for (int i = 0; i < n_in; ++i) {
        switch (in_sizes[i]) {
            case 1024:   A  = (const float*)d_in[i]; break;
            case 512:    B  = (const float*)d_in[i]; break;
            case 147456: C  = (const float*)d_in[i]; break;
            case 32:     x0 = (const float*)d_in[i]; break;
            default: break;
        }
    }
    if (!A || !B || !C || !x0) {
        A  = (const float*)d_in[0];
        B  = (const float*)d_in[1];
        C  = (const float*)d_in[2];
        x0 = (const float*)d_in[5];
    }

    lqr_kernel<<<1, 256, 0, stream>>>(A, B, C, x0, (float*)d_out);
}

// Round 12
// 585.937 us; speedup vs baseline: 4.5876x; 4.1807x over previous
//
#include <hip/hip_runtime.h>

#define NS 32   // n_state
#define NI 16   // n_input
#define NA 48   // n_all
#define TT 64   // horizon
#define HT 32   // half horizon

// ---------------- FAST PATH ----------------
// Single backward Riccati sweep (64 steps) storing K_t,P_t (f32) to d_ws,
// then forward rollout (tau), then a parallel mu pass (mu_t = P_t x_t).
// 4 barriers/step; all f64 LDS tiles padded to odd stride (bank-conflict-free).
// Numerics proven in rounds 9/11: f64 state, fused exact symmetrization
// (REQUIRED: unsymmetrized recursion diverges — 126976 signature), f32 K, f32 out.
__launch_bounds__(256, 1)
__global__ void lqr_fast(const float* __restrict__ Ag,
                         const float* __restrict__ Bg,
                         const float* __restrict__ Cg,
                         const float* __restrict__ x0g,
                         float* __restrict__ out,
                         float* __restrict__ Kall,   // [TT][NI][NS] f32
                         float* __restrict__ Pall)   // [TT][NS][NS] f32
{
    __shared__ float  sXT[TT][NS];      //  8192 B  x trajectory (f32)
    __shared__ double sA[NS][33];       //  8448 B  (padded strides: no bank conflicts)
    __shared__ double sB[NS][17];       //  4352 B
    __shared__ double sP[NS][33];       //  8448 B  Riccati state (f64)
    __shared__ double sPA[NS][33];      //  8448 B  P*A
    __shared__ double sPB[NS][17];      //  4352 B  P*B
    __shared__ double sHs[NI][33];      //  4224 B  S^T + B^T P A
    __shared__ double sKt[NI][33];      //  4224 B  K_t (f64)
    __shared__ double sGi[NI][17];      //  2176 B  G^{-1}
    __shared__ double sPp[NS][33];      //  8448 B  Q + A^T P A
    __shared__ double sx[2][NS];        //   512 B
    __shared__ double su[NI];           //   128 B   total ~62 KB

    const int tid  = threadIdx.x;
    const int wid  = tid >> 6, lane = tid & 63;
    const int pi   = tid >> 3, pj0 = (tid & 7) * 4, pb0 = (tid & 7) * 2;
    const int ki   = tid >> 4, kj0 = (tid & 15) * 2;

    for (int idx = tid; idx < NS * NS; idx += 256) {
        sA[idx >> 5][idx & 31] = (double)Ag[idx];
        sP[idx >> 5][idx & 31] = 0.0;
    }
    for (int idx = tid; idx < NS * NI; idx += 256) sB[idx >> 4][idx & 15] = (double)Bg[idx];
    __syncthreads();

    // ---- backward sweep: 64 steps, 4 barriers each ----
    for (int t = TT - 1; t >= 0; --t) {
        const float* Ct = Cg + t * NA * NA;   // [48][48] row-major

        // phase 1: PA = P*A (4 cols), PB = P*B (2 cols) per thread
        {
            double a0 = 0, a1 = 0, a2 = 0, a3 = 0, b0 = 0, b1 = 0;
            for (int k = 0; k < NS; ++k) {
                const double p = sP[pi][k];
                a0 += p * sA[k][pj0 + 0]; a1 += p * sA[k][pj0 + 1];
                a2 += p * sA[k][pj0 + 2]; a3 += p * sA[k][pj0 + 3];
                b0 += p * sB[k][pb0 + 0]; b1 += p * sB[k][pb0 + 1];
            }
            sPA[pi][pj0 + 0] = a0; sPA[pi][pj0 + 1] = a1;
            sPA[pi][pj0 + 2] = a2; sPA[pi][pj0 + 3] = a3;
            sPB[pi][pb0 + 0] = b0; sPB[pi][pb0 + 1] = b1;
        }
        __syncthreads();                                   // barrier A

        // phase 2 (overlapped): wave0 -> G^{-1} (register GJ via __shfl);
        //                       waves1-3 -> Hs, Pp
        if (wid == 0) {
            const int ri = lane & 15, cg = lane >> 4, jb = cg * 4;
            double g0 = (double)Ct[(NS + ri) * NA + NS + jb + 0];
            double g1 = (double)Ct[(NS + ri) * NA + NS + jb + 1];
            double g2 = (double)Ct[(NS + ri) * NA + NS + jb + 2];
            double g3 = (double)Ct[(NS + ri) * NA + NS + jb + 3];
            for (int k = 0; k < NS; ++k) {
                const double b = sB[k][ri];
                g0 += b * sPB[k][jb + 0]; g1 += b * sPB[k][jb + 1];
                g2 += b * sPB[k][jb + 2]; g3 += b * sPB[k][jb + 3];
            }
#pragma unroll
            for (int k = 0; k < NI; ++k) {
                const double myslot = ((k & 3) == 0) ? g0 : ((k & 3) == 1) ? g1
                                     : ((k & 3) == 2) ? g2 : g3;
                const int    plv  = k + ((k >> 2) << 4);      // lane of (k,k)
                const double piv  = __shfl(myslot, plv, 64);
                const double cv   = __shfl(myslot, ri + ((k >> 2) << 4), 64); // (ri,k)
                const double pr0  = __shfl(g0, k + (cg << 4), 64);            // (k,jb+j)
                const double pr1  = __shfl(g1, k + (cg << 4), 64);
                const double pr2  = __shfl(g2, k + (cg << 4), 64);
                const double pr3  = __shfl(g3, k + (cg << 4), 64);
                const double ip   = 1.0 / piv;
                const bool   rk   = (ri == k);
                g0 = rk ? ((jb + 0 == k) ? ip : pr0 * ip)
                        : ((jb + 0 == k) ? -cv * ip : g0 - cv * pr0 * ip);
                g1 = rk ? ((jb + 1 == k) ? ip : pr1 * ip)
                        : ((jb + 1 == k) ? -cv * ip : g1 - cv * pr1 * ip);
                g2 = rk ? ((jb + 2 == k) ? ip : pr2 * ip)
                        : ((jb + 2 == k) ? -cv * ip : g2 - cv * pr2 * ip);
                g3 = rk ? ((jb + 3 == k) ? ip : pr3 * ip)
                        : ((jb + 3 == k) ? -cv * ip : g3 - cv * pr3 * ip);
            }
            sGi[ri][jb + 0] = g0; sGi[ri][jb + 1] = g1;
            sGi[ri][jb + 2] = g2; sGi[ri][jb + 3] = g3;
        } else {
            const int e0 = tid - 64;
            for (int e = e0; e < NI * NS; e += 192) {
                const int i = e >> 5, j = e & 31;
                double acc = (double)Ct[j * NA + NS + i];
                for (int k = 0; k < NS; ++k) acc += sB[k][i] * sPA[k][j];
                sHs[i][j] = acc;
            }
            for (int e = e0; e < NS * NS; e += 192) {
                const int i = e >> 5, j = e & 31;
                double acc = (double)Ct[i * NA + j];
                for (int k = 0; k < NS; ++k) acc += sA[k][i] * sPA[k][j];
                sPp[i][j] = acc;
            }
        }
        __syncthreads();                                   // barrier B

        // phase 3: K = G^{-1} Hs (2 cols per thread); store f32 K to d_ws
        {
            double a0 = 0, a1 = 0;
            for (int k = 0; k < NI; ++k) {
                const double g = sGi[ki][k];
                a0 += g * sHs[k][kj0 + 0];
                a1 += g * sHs[k][kj0 + 1];
            }
            sKt[ki][kj0 + 0] = a0; sKt[ki][kj0 + 1] = a1;
            Kall[t * NI * NS + ki * NS + kj0 + 0] = (float)a0;
            Kall[t * NI * NS + ki * NS + kj0 + 1] = (float)a1;
        }
        __syncthreads();                                   // barrier C

        // phase 4: P_t = sym(Pp - Hs^T K); store f32 P to d_ws
        {
            double a0 = sPp[pi][pj0 + 0], a1 = sPp[pi][pj0 + 1];
            double a2 = sPp[pi][pj0 + 2], a3 = sPp[pi][pj0 + 3];
            for (int k = 0; k < NI; ++k) {
                const double h = sHs[k][pi];
                a0 -= h * sKt[k][pj0 + 0]; a1 -= h * sKt[k][pj0 + 1];
                a2 -= h * sKt[k][pj0 + 2]; a3 -= h * sKt[k][pj0 + 3];
            }
            double b0 = sPp[pj0 + 0][pi], b1 = sPp[pj0 + 1][pi];
            double b2 = sPp[pj0 + 2][pi], b3 = sPp[pj0 + 3][pi];
            for (int k = 0; k < NI; ++k) {
                const double hk = sKt[k][pi];
                b0 -= sHs[k][pj0 + 0] * hk; b1 -= sHs[k][pj0 + 1] * hk;
                b2 -= sHs[k][pj0 + 2] * hk; b3 -= sHs[k][pj0 + 3] * hk;
            }
            const double r0 = 0.5 * (a0 + b0), r1 = 0.5 * (a1 + b1);
            const double r2 = 0.5 * (a2 + b2), r3 = 0.5 * (a3 + b3);
            sP[pi][pj0 + 0] = r0; sP[pi][pj0 + 1] = r1;
            sP[pi][pj0 + 2] = r2; sP[pi][pj0 + 3] = r3;
            float* Pt = Pall + t * NS * NS + pi * NS + pj0;
            Pt[0] = (float)r0; Pt[1] = (float)r1; Pt[2] = (float)r2; Pt[3] = (float)r3;
        }
        __syncthreads();                                   // barrier D
    }

    // ---- forward rollout: tau (x + u), record x trajectory ----
    if (tid < NS) sx[0][tid] = (double)x0g[tid];
    __syncthreads();
    int cur = 0;
    for (int t = 0; t < TT; ++t) {
        if (tid < NS) {
            const float xv = (float)sx[cur][tid];
            sXT[t][tid] = xv;
            out[t * NA + tid] = xv;
        } else if (tid >= 64 && tid < 64 + NI) {
            const int i = tid - 64;
            const float* Kt = Kall + t * NI * NS + i * NS;
            double acc = 0.0;
            for (int k = 0; k < NS; ++k) acc += (double)Kt[k] * sx[cur][k];
            su[i] = -acc;
            out[t * NA + NS + i] = (float)(-acc);
        }
        __syncthreads();
        if (t < TT - 1) {
            if (tid < NS) {
                double acc = 0.0;
                for (int k = 0; k < NS; ++k) acc += sA[tid][k] * sx[cur][k];
                for (int k = 0; k < NI; ++k) acc += sB[tid][k] * su[k];
                sx[cur ^ 1][tid] = acc;
            }
            __syncthreads();
            cur ^= 1;
        }
    }
    __syncthreads();

    // ---- mu pass: mu_t = P_t x_t (parallel over 2048 dots); mu_0 negated ----
    for (int e = tid; e < TT * NS; e += 256) {
        const int t = e >> 5, i = e & 31;
        const float* Pt = Pall + t * NS * NS + i * NS;
        double acc = 0.0;
        for (int k = 0; k < NS; ++k) acc += (double)Pt[k] * (double)sXT[t][k];
        if (t == 0) acc = -acc;
        out[NA * TT + t * NS + i] = (float)acc;
    }
}

// ---------------- FALLBACK (round-11, passing) — used if ws_size < 384 KB ----
__launch_bounds__(256, 1)
__global__ void lqr_kernel_fb(const float* __restrict__ Ag,
                              const float* __restrict__ Bg,
                              const float* __restrict__ Cg,
                              const float* __restrict__ x0g,
                              float* __restrict__ out)
{
    __shared__ float  sKh[HT][NI][NS];
    __shared__ float  sXT[TT][NS];
    __shared__ double sA[NS][NS];
    __shared__ double sB[NS][NI];
    __shared__ double sP[NS][NS];
    __shared__ double sPA[NS][NS];
    __shared__ double sPB[NS][NI];
    __shared__ double sHs[NI][NS];
    __shared__ double sKt[NI][NS];
    __shared__ double sGi[NI][NI];
    __shared__ double sPp[NS][NS];
    __shared__ double sx[2][NS];
    __shared__ double su[NI];

    const int tid  = threadIdx.x;
    const int wid  = tid >> 6, lane = tid & 63;
    const int pi   = tid >> 3, pj0 = (tid & 7) * 4, pb0 = (tid & 7) * 2;
    const int ki   = tid >> 4, kj0 = (tid & 15) * 2;

    for (int idx = tid; idx < NS * NS; idx += 256) sA[idx >> 5][idx & 31] = (double)Ag[idx];
    for (int idx = tid; idx < NS * NI; idx += 256) sB[idx >> 4][idx & 15] = (double)Bg[idx];
    __syncthreads();

    auto step = [&](int t, bool storeK, int kbase, bool emitMu) {
        const float* Ct = Cg + t * NA * NA;
        {
            double a0 = 0, a1 = 0, a2 = 0, a3 = 0, b0 = 0, b1 = 0;
            for (int k = 0; k < NS; ++k) {
                const double p = sP[pi][k];
                a0 += p * sA[k][pj0 + 0]; a1 += p * sA[k][pj0 + 1];
                a2 += p * sA[k][pj0 + 2]; a3 += p * sA[k][pj0 + 3];
                b0 += p * sB[k][pb0 + 0]; b1 += p * sB[k][pb0 + 1];
            }
            sPA[pi][pj0 + 0] = a0; sPA[pi][pj0 + 1] = a1;
            sPA[pi][pj0 + 2] = a2; sPA[pi][pj0 + 3] = a3;
            sPB[pi][pb0 + 0] = b0; sPB[pi][pb0 + 1] = b1;
        }
        __syncthreads();
        if (wid == 0) {
            const int ri = lane & 15, cg = lane >> 4, jb = cg * 4;
            double g0 = (double)Ct[(NS + ri) * NA + NS + jb + 0];
            double g1 = (double)Ct[(NS + ri) * NA + NS + jb + 1];
            double g2 = (double)Ct[(NS + ri) * NA + NS + jb + 2];
            double g3 = (double)Ct[(NS + ri) * NA + NS + jb + 3];
            for (int k = 0; k < NS; ++k) {
                const double b = sB[k][ri];
                g0 += b * sPB[k][jb + 0]; g1 += b * sPB[k][jb + 1];
                g2 += b * sPB[k][jb + 2]; g3 += b * sPB[k][jb + 3];
            }
#pragma unroll
            for (int k = 0; k < NI; ++k) {
                const double myslot = ((k & 3) == 0) ? g0 : ((k & 3) == 1) ? g1
                                     : ((k & 3) == 2) ? g2 : g3;
                const int    plv  = k + ((k >> 2) << 4);
                const double piv  = __shfl(myslot, plv, 64);
                const double cv   = __shfl(myslot, ri + ((k >> 2) << 4), 64);
                const double pr0  = __shfl(g0, k + (cg << 4), 64);
                const double pr1  = __shfl(g1, k + (cg << 4), 64);
                const double pr2  = __shfl(g2, k + (cg << 4), 64);
                const double pr3  = __shfl(g3, k + (cg << 4), 64);
                const double ip   = 1.0 / piv;
                const bool   rk   = (ri == k);
                g0 = rk ? ((jb + 0 == k) ? ip : pr0 * ip)
                        : ((jb + 0 == k) ? -cv * ip : g0 - cv * pr0 * ip);
                g1 = rk ? ((jb + 1 == k) ? ip : pr1 * ip)
                        : ((jb + 1 == k) ? -cv * ip : g1 - cv * pr1 * ip);
                g2 = rk ? ((jb + 2 == k) ? ip : pr2 * ip)
                        : ((jb + 2 == k) ? -cv * ip : g2 - cv * pr2 * ip);
                g3 = rk ? ((jb + 3 == k) ? ip : pr3 * ip)
                        : ((jb + 3 == k) ? -cv * ip : g3 - cv * pr3 * ip);
            }
            sGi[ri][jb + 0] = g0; sGi[ri][jb + 1] = g1;
            sGi[ri][jb + 2] = g2; sGi[ri][jb + 3] = g3;
        } else {
            const int e0 = tid - 64;
            for (int e = e0; e < NI * NS; e += 192) {
                const int i = e >> 5, j = e & 31;
                double acc = (double)Ct[j * NA + NS + i];
                for (int k = 0; k < NS; ++k) acc += sB[k][i] * sPA[k][j];
                sHs[i][j] = acc;
            }
            for (int e = e0; e < NS * NS; e += 192) {
                const int i = e >> 5, j = e & 31;
                double acc = (double)Ct[i * NA + j];
                for (int k = 0; k < NS; ++k) acc += sA[k][i] * sPA[k][j];
                sPp[i][j] = acc;
            }
        }
        __syncthreads();
        {
            double a0 = 0, a1 = 0;
            for (int k = 0; k < NI; ++k) {
                const double g = sGi[ki][k];
                a0 += g * sHs[k][kj0 + 0];
                a1 += g * sHs[k][kj0 + 1];
            }
            sKt[ki][kj0 + 0] = a0; sKt[ki][kj0 + 1] = a1;
            if (storeK) {
                sKh[t - kbase][ki][kj0 + 0] = (float)a0;
                sKh[t - kbase][ki][kj0 + 1] = (float)a1;
            }
        }
        __syncthreads();
        {
            double a0 = sPp[pi][pj0 + 0], a1 = sPp[pi][pj0 + 1];
            double a2 = sPp[pi][pj0 + 2], a3 = sPp[pi][pj0 + 3];
            for (int k = 0; k < NI; ++k) {
                const double h = sHs[k][pi];
                a0 -= h * sKt[k][pj0 + 0]; a1 -= h * sKt[k][pj0 + 1];
                a2 -= h * sKt[k][pj0 + 2]; a3 -= h * sKt[k][pj0 + 3];
            }
            double b0 = sPp[pj0 + 0][pi], b1 = sPp[pj0 + 1][pi];
            double b2 = sPp[pj0 + 2][pi], b3 = sPp[pj0 + 3][pi];
            for (int k = 0; k < NI; ++k) {
                const double hk = sKt[k][pi];
                b0 -= sHs[k][pj0 + 0] * hk; b1 -= sHs[k][pj0 + 1] * hk;
                b2 -= sHs[k][pj0 + 2] * hk; b3 -= sHs[k][pj0 + 3] * hk;
            }
            sP[pi][pj0 + 0] = 0.5 * (a0 + b0); sP[pi][pj0 + 1] = 0.5 * (a1 + b1);
            sP[pi][pj0 + 2] = 0.5 * (a2 + b2); sP[pi][pj0 + 3] = 0.5 * (a3 + b3);
        }
        __syncthreads();
        if (emitMu && tid < NS) {
            double acc = 0.0;
            for (int k = 0; k < NS; ++k) acc += sP[tid][k] * (double)sXT[t][k];
            if (t == 0) acc = -acc;
            out[NA * TT + t * NS + tid] = (float)acc;
        }
    };

    auto sweep = [&](int tlo, int klo, int khi, bool emitMu) {
        for (int idx = tid; idx < NS * NS; idx += 256) sP[idx >> 5][idx & 31] = 0.0;
        __syncthreads();
        for (int t = TT - 1; t >= tlo; --t)
            step(t, (t >= klo && t < khi), klo, emitMu);
    };

    int cur = 0;
    auto forward = [&](int t0, int t1, int kbase) {
        for (int t = t0; t < t1; ++t) {
            if (tid < NS) {
                const float xv = (float)sx[cur][tid];
                sXT[t][tid] = xv;
                out[t * NA + tid] = xv;
            } else if (tid >= 64 && tid < 64 + NI) {
                const int i = tid - 64;
                double acc = 0.0;
                for (int k = 0; k < NS; ++k)
                    acc += (double)sKh[t - kbase][i][k] * sx[cur][k];
                su[i] = -acc;
                out[t * NA + NS + i] = (float)(-acc);
            }
            __syncthreads();
            if (t < TT - 1) {
                if (tid < NS) {
                    double acc = 0.0;
                    for (int k = 0; k < NS; ++k) acc += sA[tid][k] * sx[cur][k];
                    for (int k = 0; k < NI; ++k) acc += sB[tid][k] * su[k];
                    sx[cur ^ 1][tid] = acc;
                }
                __syncthreads();
                cur ^= 1;
            }
        }
    };

    sweep(0, 0, HT, false);
    if (tid < NS) sx[0][tid] = (double)x0g[tid];
    __syncthreads();
    forward(0, HT, 0);
    sweep(HT, HT, TT, false);
    forward(HT, TT, HT);
    sweep(0, 0, 0, true);
}

extern "C" void kernel_launch(void* const* d_in, const int* in_sizes, int n_in,
                              void* d_out, int out_size, void* d_ws, size_t ws_size,
                              hipStream_t stream) {
    // Bind by element count (A=1024, B=512, C=147456, x0=32), fallback dict order.
    const float *A = nullptr, *B = nullptr, *C = nullptr, *x0 = nullptr;
    for (int i = 0; i < n_in; ++i) {
        switch (in_sizes[i]) {
            case 1024:   A  = (const float*)d_in[i]; break;
            case 512:    B  = (const float*)d_in[i]; break;
            case 147456: C  = (const float*)d_in[i]; break;
            case 32:     x0 = (const float*)d_in[i]; break;
            default: break;
        }
    }
    if (!A || !B || !C || !x0) {
        A  = (const float*)d_in[0];
        B  = (const float*)d_in[1];
        C  = (const float*)d_in[2];
        x0 = (const float*)d_in[5];
    }

    const size_t need = (size_t)(TT * NI * NS + TT * NS * NS) * sizeof(float); // 384 KB
    if (d_ws != nullptr && ws_size >= need) {
        float* Kall = (float*)d_ws;
        float* Pall = Kall + TT * NI * NS;
        lqr_fast<<<1, 256, 0, stream>>>(A, B, C, x0, (float*)d_out, Kall, Pall);
    } else {
        lqr_kernel_fb<<<1, 256, 0, stream>>>(A, B, C, x0, (float*)d_out);
    }
}